// Round 6
// baseline (318.130 us; speedup 1.0000x reference)
//
#include <hip/hip_runtime.h>
#include <hip/hip_bf16.h>
#include <stdint.h>

typedef __attribute__((ext_vector_type(8))) short v8s;
typedef __attribute__((ext_vector_type(8))) __bf16 bf16x8;
typedef __attribute__((ext_vector_type(4))) float v4f;

__device__ __forceinline__ unsigned short f2bf(float f) {
  unsigned int u = __float_as_uint(f);
  u += 0x7fff + ((u >> 16) & 1);
  return (unsigned short)(u >> 16);
}
__device__ __forceinline__ float bf2f(unsigned short h) {
  return __uint_as_float(((unsigned int)h) << 16);
}

#define LGKM0 asm volatile("s_waitcnt lgkmcnt(0)" ::: "memory")
#define VMC6  asm volatile("s_waitcnt vmcnt(6)" ::: "memory")
#define VMC0  asm volatile("s_waitcnt vmcnt(0)" ::: "memory")
#define SCHEDB __builtin_amdgcn_sched_barrier(0)
#define BAR __builtin_amdgcn_s_barrier()

// ---------------- cast f32 -> bf16 ----------------
__global__ void cast_f32_bf16(const float* __restrict__ s, unsigned short* __restrict__ d, int n) {
  int i = (blockIdx.x * blockDim.x + threadIdx.x) * 4;
  if (i >= n) return;
  float4 v = *(const float4*)(s + i);
  ushort4 o;
  o.x = f2bf(v.x); o.y = f2bf(v.y); o.z = f2bf(v.z); o.w = f2bf(v.w);
  *(ushort4*)(d + i) = o;
}

// ---------------- 8-phase pipelined GEMM: C[M,N] = A[M,K]*B[N,K]^T + bias ----
// BM=BN=256, BK=64, 512 thr (8 waves as 2M x 4N, per-wave 128x64 = acc[8][4]).
// LDS 128KB: 2 K-tile buffers. Per K-tile 4 phases; phase 1 caches all B-frags
// in regs (frees B region), phases p read A phase-chunk p. Each phase stages
// one 16KB unit (2 gload_lds/wave) into a region consumed by the previous
// phase's end barrier. vmcnt(6) only at phases 4/8. Last iter peeled (vmcnt 0).
#define GBM 256
#define GBK 64

__device__ __forceinline__ void gload_lds16(const void* g, void* l) {
  __builtin_amdgcn_global_load_lds(
      (const __attribute__((address_space(1))) void*)g,
      (__attribute__((address_space(3))) void*)l,
      16, 0, 0);
}

// A chunk layout: chunk p holds global tile-rows {32p..32p+31} u {128+32p..+31};
// row-in-chunk ric: g = 32p + ric (ric<32) else g = 32p + ric + 96.
template <int OUT>
__global__ __launch_bounds__(512, 2) void gemm_pipe(
    const unsigned short* __restrict__ A,   // M x K
    const unsigned short* __restrict__ B,   // N x K
    const float* __restrict__ bias0,
    const float* __restrict__ bias1,
    const float* __restrict__ bias2,
    void* __restrict__ D0,                  // OUT=1: Qb ; OUT=0: f32 out
    void* __restrict__ D1,                  // Kb
    void* __restrict__ D2,                  // Vt
    int K, int gnx)                         // gnx = gridN/8
{
  __shared__ __align__(16) unsigned short As[2][4][64][64];   // 64KB
  __shared__ __align__(16) unsigned short Bs[2][2][128][64];  // 64KB

  const int bid = blockIdx.x;
  const int xcd = bid & 7;
  const int r   = bid >> 3;
  const int by  = r / gnx;
  const int bx  = xcd * gnx + (r % gnx);
  const int tm  = by * 256;
  const int tn  = bx * 256;

  const int tid  = threadIdx.x;
  const int lane = tid & 63;
  const int wid  = tid >> 6;            // 0..7
  const int wm   = wid >> 2;            // 0..1
  const int wn   = wid & 3;             // 0..3

  const int srow = lane >> 3;           // 0..7
  const int scb  = lane & 7;
  const int gco  = (scb ^ srow) * 8;    // XOR-swizzled source col chunk

  const unsigned short* Ag = A + (size_t)tm * K;
  const unsigned short* Bg = B + (size_t)tn * K;

  v4f acc[8][4];
#pragma unroll
  for (int m = 0; m < 8; ++m)
#pragma unroll
    for (int n = 0; n < 4; ++n)
      acc[m][n] = (v4f){0.f, 0.f, 0.f, 0.f};

  bf16x8 av[2][2], bv[4][2];
  const int nt = K / GBK;               // 32

  // stage one 16KB A unit (chunks 2u,2u+1) of tile kt into buf (2 gloads/wave)
#define STAGE_A(buf, kt, u)                                                      \
  if ((kt) < nt) {                                                               \
    const int c_ = 2 * (u) + (wid >> 2);                                         \
    _Pragma("unroll")                                                            \
    for (int j = 0; j < 2; ++j) {                                                \
      const int rb_ = (wid & 3) * 16 + j * 8;                                    \
      const int ric_ = rb_ + srow;                                               \
      const int g_ = 32 * c_ + ric_ + ((rb_ >= 32) ? 96 : 0);                    \
      gload_lds16(Ag + (size_t)g_ * K + (kt) * GBK + gco, &As[buf][c_][rb_][0]); \
    }                                                                            \
  }

  // stage one 16KB B half (rows h*128..+127) of tile kt into buf
#define STAGE_B(buf, kt, h)                                                      \
  if ((kt) < nt) {                                                               \
    _Pragma("unroll")                                                            \
    for (int j = 0; j < 2; ++j) {                                                \
      const int rb_ = (wid * 2 + j) * 8;                                         \
      gload_lds16(Bg + (size_t)((h) * 128 + rb_ + srow) * K + (kt) * GBK + gco,  \
                  &Bs[buf][h][rb_][0]);                                          \
    }                                                                            \
  }

#define PHASE(buf, p, STAGE_STMT, WAIT_STMT)                                     \
  {                                                                              \
    if ((p) == 0) {                                                              \
      _Pragma("unroll")                                                          \
      for (int nf = 0; nf < 4; ++nf) {                                           \
        const int row_ = wn * 64 + nf * 16 + (lane & 15);                        \
        _Pragma("unroll")                                                        \
        for (int ks = 0; ks < 2; ++ks) {                                         \
          const int cl_ = ks * 4 + (lane >> 4);                                  \
          bv[nf][ks] = *(const bf16x8*)&Bs[buf][row_ >> 7][row_ & 127]           \
                           [(cl_ ^ (lane & 7)) * 8];                             \
        }                                                                        \
      }                                                                          \
    }                                                                            \
    _Pragma("unroll")                                                            \
    for (int mf = 0; mf < 2; ++mf) {                                             \
      const int ric_ = wm * 32 + mf * 16 + (lane & 15);                          \
      _Pragma("unroll")                                                          \
      for (int ks = 0; ks < 2; ++ks) {                                           \
        const int cl_ = ks * 4 + (lane >> 4);                                    \
        av[mf][ks] = *(const bf16x8*)&As[buf][p][ric_][(cl_ ^ (lane & 7)) * 8];  \
      }                                                                          \
    }                                                                            \
    STAGE_STMT;                                                                  \
    SCHEDB;                                                                      \
    BAR;                                                                         \
    LGKM0;                                                                       \
    SCHEDB;                                                                      \
    __builtin_amdgcn_s_setprio(1);                                               \
    _Pragma("unroll")                                                            \
    for (int ks = 0; ks < 2; ++ks)                                               \
      _Pragma("unroll")                                                          \
      for (int mf = 0; mf < 2; ++mf)                                             \
        _Pragma("unroll")                                                        \
        for (int nf = 0; nf < 4; ++nf)                                           \
          acc[2 * (p) + mf][nf] = __builtin_amdgcn_mfma_f32_16x16x32_bf16(       \
              av[mf][ks], bv[nf][ks], acc[2 * (p) + mf][nf], 0, 0, 0);           \
    __builtin_amdgcn_s_setprio(0);                                               \
    SCHEDB;                                                                      \
    WAIT_STMT;                                                                   \
    BAR;                                                                         \
  }

#define NOWAIT

  // prologue: T0 fully (8 loads/wave), T1 B0,B1,A01 (6 loads/wave)
  STAGE_B(0, 0, 0); STAGE_B(0, 0, 1); STAGE_A(0, 0, 0); STAGE_A(0, 0, 1);
  STAGE_B(1, 1, 0); STAGE_B(1, 1, 1); STAGE_A(1, 1, 0);
  VMC6;
  BAR;

  for (int i = 0; i < nt / 2 - 1; ++i) {
    const int t2 = 2 * i + 2, t3 = 2 * i + 3;
    PHASE(0, 0, STAGE_A(1, 2 * i + 1, 1), NOWAIT);  // ph1: T_{2i+1}.A23
    PHASE(0, 1, STAGE_B(0, t2, 0), NOWAIT);         // ph2: T_{2i+2}.B0
    PHASE(0, 2, STAGE_B(0, t2, 1), NOWAIT);         // ph3: T_{2i+2}.B1
    PHASE(0, 3, STAGE_A(0, t2, 0), VMC6);           // ph4: T_{2i+2}.A01
    PHASE(1, 0, STAGE_A(0, t2, 1), NOWAIT);         // ph5: T_{2i+2}.A23
    PHASE(1, 1, STAGE_B(1, t3, 0), NOWAIT);         // ph6: T_{2i+3}.B0
    PHASE(1, 2, STAGE_B(1, t3, 1), NOWAIT);         // ph7: T_{2i+3}.B1
    PHASE(1, 3, STAGE_A(1, t3, 0), VMC6);           // ph8: T_{2i+3}.A01
  }
  // peeled last iteration (i = nt/2-1): no new stages; drain with vmcnt(0)
  {
    const int i = nt / 2 - 1;
    PHASE(0, 0, STAGE_A(1, 2 * i + 1, 1), NOWAIT);
    PHASE(0, 1, , NOWAIT);
    PHASE(0, 2, , NOWAIT);
    PHASE(0, 3, , VMC0);                            // T_{nt-1} fully landed
    PHASE(1, 0, , NOWAIT);
    PHASE(1, 1, , NOWAIT);
    PHASE(1, 2, , NOWAIT);
    PHASE(1, 3, , NOWAIT);
  }

#undef STAGE_A
#undef STAGE_B
#undef PHASE
#undef NOWAIT

  // epilogue
  const int rr0 = tm + wm * 128 + (lane >> 4) * 4;
  const int cc0 = tn + wn * 64 + (lane & 15);

  if (OUT == 0) {
    float* Dp = (float*)D0;
#pragma unroll
    for (int n = 0; n < 4; ++n) {
      const int col = cc0 + n * 16;
      const float bz = bias0[col];
#pragma unroll
      for (int m = 0; m < 8; ++m) {
#pragma unroll
        for (int rg = 0; rg < 4; ++rg) {
          const int rr = rr0 + m * 16 + rg;
          Dp[(size_t)rr * 2048 + col] = acc[m][n][rg] + bz;
        }
      }
    }
  } else {
    const int sid = tn >> 11;           // whole 256-col block in one QKV slice
    const float* bp = (sid == 0) ? bias0 : (sid == 1) ? bias1 : bias2;
    unsigned short* Dq = (unsigned short*)((sid == 0) ? D0 : (sid == 1) ? D1 : D2);
#pragma unroll
    for (int n = 0; n < 4; ++n) {
      const int col = cc0 + n * 16;
      const int c2 = col & 2047;
      const float bz = bp[c2];
#pragma unroll
      for (int m = 0; m < 8; ++m) {
#pragma unroll
        for (int rg = 0; rg < 4; ++rg) {
          const int rr = rr0 + m * 16 + rg;
          const float val = acc[m][n][rg] + bz;
          if (sid < 2) {
            Dq[(size_t)rr * 2048 + c2] = f2bf(val);
          } else {
            const int bb = rr >> 11, ll = rr & 2047;
            const int hh = c2 >> 7, dd = c2 & 127;
            Dq[(((size_t)(bb * 16 + hh)) * 2048 + ll) * 128 + dd] = f2bf(val);
          }
        }
      }
    }
  }
}

// ---------------- RMSNorm (+ channel-shift mix for Q), writes transposed [b,h,l,d] ----------------
__global__ __launch_bounds__(256) void rmsnorm_mix(
    const unsigned short* __restrict__ Qb, const unsigned short* __restrict__ Kb,
    unsigned short* __restrict__ Qt, unsigned short* __restrict__ Kt,
    const float* __restrict__ gq, const float* __restrict__ gk,
    const float* __restrict__ wmix)
{
  const int row = blockIdx.x;            // b*L + l
  const bool isQ = (blockIdx.y == 0);
  const unsigned short* src = (isQ ? Qb : Kb) + (size_t)row * 2048;
  unsigned short* dstbase = isQ ? Qt : Kt;
  const float* g = isQ ? gq : gk;
  const int b = row >> 11, l = row & 2047;

  __shared__ float sv[2048];
  __shared__ float red[4];

  const int t = threadIdx.x;
  v8s raw = *(const v8s*)(src + t * 8);
  float x[8];
  float ss = 0.f;
#pragma unroll
  for (int j = 0; j < 8; ++j) { x[j] = bf2f((unsigned short)raw[j]); ss += x[j] * x[j]; }
#pragma unroll
  for (int o = 32; o > 0; o >>= 1) ss += __shfl_xor(ss, o, 64);
  if ((t & 63) == 0) red[t >> 6] = ss;
  __syncthreads();
  const float tot = red[0] + red[1] + red[2] + red[3];
  const float inv = rsqrtf(tot * (1.0f / 2048.0f) + 1e-6f);

  const int h = t >> 4;
  unsigned short* dst = dstbase + (((size_t)(b * 16 + h)) * 2048 + l) * 128 + ((t * 8) & 127);

  if (isQ) {
#pragma unroll
    for (int j = 0; j < 8; ++j) sv[t * 8 + j] = x[j] * inv * g[t * 8 + j];
    __syncthreads();
    const float scale = 0.08838834764831845f;  // 1/sqrt(128)
    const float w0 = wmix[0], w1 = wmix[1], w2 = wmix[2], w3 = wmix[3], w4 = wmix[4];
    v8s ov;
#pragma unroll
    for (int j = 0; j < 8; ++j) {
      const int idx = t * 8 + j;
      const int hb = idx & ~127;
      const int d  = idx & 127;
      float a = w0 * sv[hb + d]
              + w1 * sv[hb + ((d - 1) & 127)]
              + w2 * sv[hb + ((d - 2) & 127)]
              + w3 * sv[hb + ((d - 4) & 127)]
              + w4 * sv[hb + ((d - 8) & 127)];
      ov[j] = (short)f2bf(a * scale);
    }
    *(v8s*)dst = ov;
  } else {
    v8s ov;
#pragma unroll
    for (int j = 0; j < 8; ++j) ov[j] = (short)f2bf(x[j] * inv * g[t * 8 + j]);
    *(v8s*)dst = ov;
  }
}

// ---------------- attention over 16 fixed sequence shifts (head-major) ----------------
__global__ __launch_bounds__(256) void attention_k(
    const unsigned short* __restrict__ Qt,
    const unsigned short* __restrict__ Kt,
    const unsigned short* __restrict__ Vt,
    unsigned short* __restrict__ AO)
{
  const int bid = blockIdx.x;            // (b,h,lc)
  const int b  = bid >> 9;
  const int h  = (bid >> 5) & 15;
  const int lc = bid & 31;
  const int l0 = lc * 64;

  const int t = threadIdx.x;
  const int l = t >> 2;                  // 0..63
  const int q = t & 3;                   // dim quarter (32 elems)

  __shared__ float sc[64][17];

  const size_t plane = ((size_t)(b * 16 + h)) * 2048 * 128;
  const int myl = l0 + l;

  v8s qv[4];
  {
    const unsigned short* qp = Qt + plane + (size_t)myl * 128 + q * 32;
#pragma unroll
    for (int i = 0; i < 4; ++i) qv[i] = *(const v8s*)(qp + i * 8);
  }

  const int SH[16] = {0, 1, -1, 3, -3, 7, -7, 20, -20, 53, -53, 141, -141, 380, -380, 1024};

  // pass 1: scores
#pragma unroll 4
  for (int s = 0; s < 16; ++s) {
    const int row = (myl - SH[s]) & 2047;
    const unsigned short* kp = Kt + plane + (size_t)row * 128 + q * 32;
    float dot = 0.f;
#pragma unroll
    for (int i = 0; i < 4; ++i) {
      v8s kv = *(const v8s*)(kp + i * 8);
#pragma unroll
      for (int j = 0; j < 8; ++j)
        dot += bf2f((unsigned short)kv[j]) * bf2f((unsigned short)qv[i][j]);
    }
    dot += __shfl_xor(dot, 1, 64);
    dot += __shfl_xor(dot, 2, 64);
    if (q == 0) sc[l][s] = dot;
  }
  __syncthreads();

  // softmax over s
  {
    float v0[16];
#pragma unroll
    for (int s = 0; s < 16; ++s) v0[s] = sc[l][s];
    float mx = v0[0];
#pragma unroll
    for (int s = 1; s < 16; ++s) mx = fmaxf(mx, v0[s]);
    float sum = 0.f;
    float e[4];
#pragma unroll
    for (int s = 0; s < 16; ++s) {
      const float ee = __expf(v0[s] - mx);
      sum += ee;
      if ((s >> 2) == q) e[s & 3] = ee;
    }
    const float inv = 1.f / sum;
#pragma unroll
    for (int i = 0; i < 4; ++i) sc[l][q * 4 + i] = e[i] * inv;
  }
  __syncthreads();

  // pass 2: output accumulate
  float o[32];
#pragma unroll
  for (int i = 0; i < 32; ++i) o[i] = 0.f;
#pragma unroll 2
  for (int s = 0; s < 16; ++s) {
    const float p = sc[l][s];
    const int row = (myl - SH[s]) & 2047;
    const unsigned short* vp = Vt + plane + (size_t)row * 128 + q * 32;
#pragma unroll
    for (int i = 0; i < 4; ++i) {
      v8s vv = *(const v8s*)(vp + i * 8);
#pragma unroll
      for (int j = 0; j < 8; ++j)
        o[i * 8 + j] += p * bf2f((unsigned short)vv[j]);
    }
  }

  unsigned short* op = AO + ((size_t)(b * 2048 + myl)) * 2048 + h * 128 + q * 32;
#pragma unroll
  for (int i = 0; i < 4; ++i) {
    v8s ov;
#pragma unroll
    for (int j = 0; j < 8; ++j) ov[j] = (short)f2bf(o[i * 8 + j]);
    *(v8s*)(op + i * 8) = ov;
  }
}

// ---------------- launch ----------------
extern "C" void kernel_launch(void* const* d_in, const int* in_sizes, int n_in,
                              void* d_out, int out_size, void* d_ws, size_t ws_size,
                              hipStream_t stream) {
  const float* x    = (const float*)d_in[0];
  const float* wq   = (const float*)d_in[1];
  const float* bq   = (const float*)d_in[2];
  const float* wk   = (const float*)d_in[3];
  const float* bk   = (const float*)d_in[4];
  const float* wv   = (const float*)d_in[5];
  const float* bv   = (const float*)d_in[6];
  const float* gq   = (const float*)d_in[7];
  const float* gk   = (const float*)d_in[8];
  const float* wmix = (const float*)d_in[9];
  const float* wo   = (const float*)d_in[10];
  const float* bo   = (const float*)d_in[11];

  const int M = 4096;      // B*L
  const int K = 2048;      // QUERY_DIM
  const int N = 2048;      // INNER
  const size_t MB = 1024 * 1024;

  char* ws = (char*)d_ws;
  // workspace (104 MB, aliased):
  unsigned short* xb    = (unsigned short*)(ws + 0 * MB);    // 16MB; dead after QKV gemm
  unsigned short* Ktr   = (unsigned short*)(ws + 0 * MB);    // alias xb
  unsigned short* wqkvb = (unsigned short*)(ws + 16 * MB);   // 24MB; dead after QKV gemm
  unsigned short* wob   = (unsigned short*)(ws + 16 * MB);   // alias wqkvb
  unsigned short* Qb    = (unsigned short*)(ws + 40 * MB);   // 16MB; dead after rmsnorm
  unsigned short* AOb   = (unsigned short*)(ws + 40 * MB);   // alias Qb
  unsigned short* Kb    = (unsigned short*)(ws + 56 * MB);   // 16MB
  unsigned short* Vt    = (unsigned short*)(ws + 72 * MB);   // 16MB (transposed V)
  unsigned short* Qtr   = (unsigned short*)(ws + 88 * MB);   // 16MB

  cast_f32_bf16<<<(M * K) / 1024, 256, 0, stream>>>(x, xb, M * K);
  cast_f32_bf16<<<(N * K) / 1024, 256, 0, stream>>>(wq, wqkvb, N * K);
  cast_f32_bf16<<<(N * K) / 1024, 256, 0, stream>>>(wk, wqkvb + (size_t)N * K, N * K);
  cast_f32_bf16<<<(N * K) / 1024, 256, 0, stream>>>(wv, wqkvb + 2 * (size_t)N * K, N * K);

  // fused QKV GEMM: M=4096, Nfused=6144 -> grid 16 x 24 = 384 blocks
  gemm_pipe<1><<<384, 512, 0, stream>>>(xb, wqkvb, bq, bk, bv, Qb, Kb, Vt, K, 3);

  cast_f32_bf16<<<(N * K) / 1024, 256, 0, stream>>>(wo, wob, N * K);  // into wqkvb slot

  rmsnorm_mix<<<dim3(M, 2), 256, 0, stream>>>(Qb, Kb, Qtr, Ktr, gq, gk, wmix);
  attention_k<<<1024, 256, 0, stream>>>(Qtr, Ktr, Vt, AOb);

  // out-proj: grid 16 x 8 = 128 blocks (each XCD owns one B-panel column)
  gemm_pipe<0><<<128, 512, 0, stream>>>(AOb, wob, bo, nullptr, nullptr, d_out, nullptr, nullptr, K, 1);
}